// Round 3
// baseline (515.639 us; speedup 1.0000x reference)
//
#include <hip/hip_runtime.h>
#include <hip/hip_bf16.h>

#define B_  4
#define S_  1024
#define DM_ 1024
#define H_  16
#define DK_ 64

typedef unsigned short u16;
typedef __attribute__((ext_vector_type(8))) short bf16x8;
typedef __attribute__((ext_vector_type(4))) float f32x4;

__device__ __forceinline__ float bf2f(u16 u) {
    union { unsigned int i; float f; } c;
    c.i = ((unsigned int)u) << 16;
    return c.f;
}
__device__ __forceinline__ u16 f2bf(float f) {
    union { float f; unsigned int i; } c;
    c.f = f;
    unsigned int x = c.i;
    unsigned int lsb = (x >> 16) & 1u;
    x += 0x7fffu + lsb;          // round-to-nearest-even
    return (u16)(x >> 16);
}

// ---------------------------------------------------------------------------
// Runtime dtype detection (one wave, parallel). fp32 inputs -> even u16s are
// float low halves (mantissa bits, ~16% land in exponent-range); bf16 inputs
// -> ~100%. flag=1 means inputs are fp32.
// ---------------------------------------------------------------------------
__global__ void detect_kernel(const u16* __restrict__ q, int* __restrict__ flag) {
    int lane = threadIdx.x & 63;
    int cnt = 0;
#pragma unroll
    for (int i = 0; i < 4; ++i) {
        u16 u = q[2 * (lane * 4 + i)];
        int e = (u >> 7) & 0xFF;
        cnt += (e >= 100 && e <= 140) ? 1 : 0;
    }
#pragma unroll
    for (int off = 1; off < 64; off <<= 1) cnt += __shfl_xor(cnt, off, 64);
    if (lane == 0) *flag = (cnt < 128) ? 1 : 0;
}

// ---------------------------------------------------------------------------
// mask (int32) -> additive bf16 bias: 0 where mask!=0, -1e9 where mask==0.
// ---------------------------------------------------------------------------
__global__ __launch_bounds__(256) void maskbias_kernel(
    const int* __restrict__ mask, u16* __restrict__ mb)
{
    size_t i = ((size_t)blockIdx.x * 256 + threadIdx.x) * 8;
    int4 m0 = *(const int4*)&mask[i];
    int4 m1 = *(const int4*)&mask[i + 4];
    const u16 NEG = f2bf(-1e9f);
    u16 o[8];
    o[0] = m0.x ? 0 : NEG; o[1] = m0.y ? 0 : NEG;
    o[2] = m0.z ? 0 : NEG; o[3] = m0.w ? 0 : NEG;
    o[4] = m1.x ? 0 : NEG; o[5] = m1.y ? 0 : NEG;
    o[6] = m1.z ? 0 : NEG; o[7] = m1.w ? 0 : NEG;
    *(uint4*)&mb[i] = *(uint4*)o;
}

// ---------------------------------------------------------------------------
// Per-head transpose: Kp (b,s,h,d) -> KpT[((b*H+h)*DK + d)*S + s].
// LDS tile padded to 65 (odd stride: scatter/gather conflicts <=2-way).
// ---------------------------------------------------------------------------
__global__ __launch_bounds__(256) void transpose_kernel(
    const u16* __restrict__ kp, u16* __restrict__ kpt)
{
    __shared__ u16 T[64][65];
    const int s0 = blockIdx.x * 64, h = blockIdx.y, b = blockIdx.z;
    const int tid = threadIdx.x;
    const size_t base = (size_t)b * S_ * DM_ + (size_t)h * DK_;
    for (int c = tid; c < 512; c += 256) {
        int row = c >> 3, cc = (c & 7) * 8;
        union { uint4 v; u16 u[8]; } x;
        x.v = *(const uint4*)&kp[base + (size_t)(s0 + row) * DM_ + cc];
#pragma unroll
        for (int j = 0; j < 8; ++j) T[row][cc + j] = x.u[j];
    }
    __syncthreads();
    const size_t baseT = (size_t)(b * H_ + h) * DK_ * S_;
    for (int c = tid; c < 512; c += 256) {
        int d = c >> 3, ss = (c & 7) * 8;
        u16 t[8];
#pragma unroll
        for (int j = 0; j < 8; ++j) t[j] = T[ss + j][d];
        *(uint4*)&kpt[baseT + (size_t)d * S_ + s0 + ss] = *(uint4*)t;
    }
}

// ---------------------------------------------------------------------------
// GEMM: C[m,n] = act(sum_k A[m,k]*W[n,k] + bias[n]); bf16 MFMA, fp32 accum.
// 128x64 tile (BK=64), 256 threads; wave w owns rows w*32..w*32+31 (2 row-
// tiles x 4 col-tiles of mfma_f32_16x16x32_bf16). Grid 2 blocks/CU for the
// big GEMMs. A_DYN/W_DYN/OUT_DYN select fp32 operand handling via *flag.
// ---------------------------------------------------------------------------
template<int ACT, int A_DYN, int W_DYN, int OUT_DYN>
__global__ __launch_bounds__(256, 2) void gemm_bias_kernel(
    const void* __restrict__ Ap, const void* __restrict__ Wp,
    const void* __restrict__ biasp, void* __restrict__ Cp,
    int M, int N, int K, const int* __restrict__ flag)
{
    __shared__ __align__(16) u16 As[128][72];
    __shared__ __align__(16) u16 Ws[64][72];

    const int f    = (A_DYN || W_DYN || OUT_DYN) ? *flag : 0;
    const bool af32 = A_DYN && f;
    const bool wf32 = W_DYN && f;

    const int m0   = blockIdx.y * 128;
    const int n0   = blockIdx.x * 64;
    const int tid  = threadIdx.x;
    const int w    = tid >> 6;
    const int lane = tid & 63;
    const int l16  = lane & 15;
    const int quad = lane >> 4;

    f32x4 acc[2][4];
#pragma unroll
    for (int rt = 0; rt < 2; ++rt)
#pragma unroll
        for (int ct = 0; ct < 4; ++ct) acc[rt][ct] = (f32x4){0.f, 0.f, 0.f, 0.f};

    for (int k0 = 0; k0 < K; k0 += 64) {
        for (int c = tid; c < 1024; c += 256) {
            int row = c >> 3, cc = (c & 7) * 8;
            if (af32) {
                const float* ap = (const float*)Ap + (size_t)(m0 + row) * K + k0 + cc;
                float4 x = *(const float4*)ap, y = *(const float4*)(ap + 4);
                u16 t[8] = {f2bf(x.x), f2bf(x.y), f2bf(x.z), f2bf(x.w),
                            f2bf(y.x), f2bf(y.y), f2bf(y.z), f2bf(y.w)};
                *(uint4*)&As[row][cc] = *(uint4*)t;
            } else {
                *(uint4*)&As[row][cc] =
                    *(const uint4*)((const u16*)Ap + (size_t)(m0 + row) * K + k0 + cc);
            }
        }
        for (int c = tid; c < 512; c += 256) {
            int row = c >> 3, cc = (c & 7) * 8;
            if (wf32) {
                const float* wp = (const float*)Wp + (size_t)(n0 + row) * K + k0 + cc;
                float4 x = *(const float4*)wp, y = *(const float4*)(wp + 4);
                u16 t[8] = {f2bf(x.x), f2bf(x.y), f2bf(x.z), f2bf(x.w),
                            f2bf(y.x), f2bf(y.y), f2bf(y.z), f2bf(y.w)};
                *(uint4*)&Ws[row][cc] = *(uint4*)t;
            } else {
                *(uint4*)&Ws[row][cc] =
                    *(const uint4*)((const u16*)Wp + (size_t)(n0 + row) * K + k0 + cc);
            }
        }
        __syncthreads();
#pragma unroll
        for (int kk = 0; kk < 2; ++kk) {
            bf16x8 a[2], b[4];
#pragma unroll
            for (int rt = 0; rt < 2; ++rt)
                a[rt] = *(const bf16x8*)&As[w * 32 + rt * 16 + l16][kk * 32 + quad * 8];
#pragma unroll
            for (int ct = 0; ct < 4; ++ct)
                b[ct] = *(const bf16x8*)&Ws[ct * 16 + l16][kk * 32 + quad * 8];
#pragma unroll
            for (int rt = 0; rt < 2; ++rt)
#pragma unroll
                for (int ct = 0; ct < 4; ++ct)
                    acc[rt][ct] = __builtin_amdgcn_mfma_f32_16x16x32_bf16(
                        a[rt], b[ct], acc[rt][ct], 0, 0, 0);
        }
        __syncthreads();
    }

    // C/D layout: row = quad*4 + r, col = l16 (m89/m91)
#pragma unroll
    for (int ct = 0; ct < 4; ++ct) {
        int col = n0 + ct * 16 + l16;
        float bv = wf32 ? ((const float*)biasp)[col] : bf2f(((const u16*)biasp)[col]);
#pragma unroll
        for (int rt = 0; rt < 2; ++rt)
#pragma unroll
            for (int r = 0; r < 4; ++r) {
                int row = m0 + w * 32 + rt * 16 + quad * 4 + r;
                float v = acc[rt][ct][r] + bv;
                if (ACT) v = v > 0.f ? v : 0.f;
                size_t idx = (size_t)row * N + col;
                if (OUT_DYN && f) ((float*)Cp)[idx] = v;
                else              ((u16*)Cp)[idx]   = f2bf(v);
            }
    }
}

// ---------------------------------------------------------------------------
// Fused attention, flash-style. One block = (b, h, 64-row q-tile).
// Changes vs R1: q fragments in registers (no q1s/q2s LDS); Kp^T staged from
// precomputed KpT (no in-kernel transpose scatter); mask as staged bf16
// additive bias; pts aliases the mask-bias array (each wave only touches its
// own 16 rows of both). LDS 36.9 KB -> 4 blocks/CU.
// ---------------------------------------------------------------------------
__global__ __launch_bounds__(256, 4) void attn_kernel(
    const u16* __restrict__ q1, const u16* __restrict__ q2,
    const u16* __restrict__ kr, const u16* __restrict__ vr,
    const u16* __restrict__ kpt, const u16* __restrict__ mb,
    u16* __restrict__ om)
{
    __shared__ __align__(16) u16 krs[64][72];
    __shared__ __align__(16) u16 vrs[64][72];
    __shared__ __align__(16) u16 kts[64][72];   // KpT tile: rows d, cols k
    __shared__ __align__(16) u16 mbs[64][72];   // mask bias; pts aliases rows w*16..

    const int qt   = blockIdx.x;
    const int h    = blockIdx.y;
    const int b    = blockIdx.z;
    const int q0   = qt * 64;
    const int tid  = threadIdx.x;
    const int w    = tid >> 6;
    const int lane = tid & 63;
    const int l16  = lane & 15;
    const int quad = lane >> 4;

    const size_t base  = (size_t)b * S_ * DM_ + (size_t)h * DK_;
    const size_t baseT = (size_t)(b * H_ + h) * DK_ * S_;

    // q fragments straight to registers: A[m=l16][k=quad*8+j]
    const int qrow = q0 + w * 16 + l16;
    bf16x8 a1[2], a2[2];
#pragma unroll
    for (int kk = 0; kk < 2; ++kk) {
        a1[kk] = *(const bf16x8*)&q1[base + (size_t)qrow * DM_ + kk * 32 + quad * 8];
        a2[kk] = *(const bf16x8*)&q2[base + (size_t)qrow * DM_ + kk * 32 + quad * 8];
    }

    float m_run[4], l_run[4];
    f32x4 oacc[4];
#pragma unroll
    for (int r = 0; r < 4; ++r) { m_run[r] = -1e30f; l_run[r] = 0.f; }
#pragma unroll
    for (int ct = 0; ct < 4; ++ct) oacc[ct] = (f32x4){0.f, 0.f, 0.f, 0.f};

    for (int kt = 0; kt < S_ / 64; ++kt) {
        const int k0 = kt * 64;
        __syncthreads();   // protects prior iteration's LDS reads
        for (int c = tid; c < 512; c += 256) {
            int row = c >> 3, cc = (c & 7) * 8;
            *(uint4*)&krs[row][cc] = *(const uint4*)&kr[base + (size_t)(k0 + row) * DM_ + cc];
            *(uint4*)&vrs[row][cc] = *(const uint4*)&vr[base + (size_t)(k0 + row) * DM_ + cc];
            *(uint4*)&kts[row][cc] = *(const uint4*)&kpt[baseT + (size_t)row * S_ + k0 + cc];
            *(uint4*)&mbs[row][cc] = *(const uint4*)&mb[((size_t)b * S_ + q0 + row) * S_ + k0 + cc];
        }
        __syncthreads();

        f32x4 s1[4], s2[4];
#pragma unroll
        for (int ct = 0; ct < 4; ++ct) {
            s1[ct] = (f32x4){0.f, 0.f, 0.f, 0.f};
            s2[ct] = (f32x4){0.f, 0.f, 0.f, 0.f};
        }
#pragma unroll
        for (int kk = 0; kk < 2; ++kk) {
#pragma unroll
            for (int ct = 0; ct < 4; ++ct) {
                bf16x8 b1 = *(const bf16x8*)&krs[ct * 16 + l16][kk * 32 + quad * 8];
                bf16x8 b2 = *(const bf16x8*)&vrs[ct * 16 + l16][kk * 32 + quad * 8];
                s1[ct] = __builtin_amdgcn_mfma_f32_16x16x32_bf16(a1[kk], b1, s1[ct], 0, 0, 0);
                s2[ct] = __builtin_amdgcn_mfma_f32_16x16x32_bf16(a2[kk], b2, s2[ct], 0, 0, 0);
            }
        }

        // additive mask bias + per-row tile max
        float tmax[4] = {-1e30f, -1e30f, -1e30f, -1e30f};
#pragma unroll
        for (int ct = 0; ct < 4; ++ct)
#pragma unroll
            for (int r = 0; r < 4; ++r) {
                float v = s1[ct][r] + bf2f(mbs[w * 16 + quad * 4 + r][ct * 16 + l16]);
                s1[ct][r] = v;
                tmax[r] = fmaxf(tmax[r], v);
            }
#pragma unroll
        for (int off = 1; off < 16; off <<= 1)
#pragma unroll
            for (int r = 0; r < 4; ++r)
                tmax[r] = fmaxf(tmax[r], __shfl_xor(tmax[r], off, 64));

        float alpha[4], newm[4];
#pragma unroll
        for (int r = 0; r < 4; ++r) {
            newm[r]  = fmaxf(m_run[r], tmax[r]);
            alpha[r] = __expf(m_run[r] - newm[r]);
            m_run[r] = newm[r];
        }

        // P~ = exp(S1-m)*S2 into mbs rows w*16.. (own slice only; same-wave
        // RAW through LDS is in-order)
        float psum[4] = {0.f, 0.f, 0.f, 0.f};
#pragma unroll
        for (int ct = 0; ct < 4; ++ct)
#pragma unroll
            for (int r = 0; r < 4; ++r) {
                float p = __expf(s1[ct][r] - newm[r]);
                psum[r] += p;
                mbs[w * 16 + quad * 4 + r][ct * 16 + l16] = f2bf(p * s2[ct][r]);
            }
#pragma unroll
        for (int off = 1; off < 16; off <<= 1)
#pragma unroll
            for (int r = 0; r < 4; ++r)
                psum[r] += __shfl_xor(psum[r], off, 64);
#pragma unroll
        for (int r = 0; r < 4; ++r) l_run[r] = l_run[r] * alpha[r] + psum[r];
#pragma unroll
        for (int ct = 0; ct < 4; ++ct)
#pragma unroll
            for (int r = 0; r < 4; ++r) oacc[ct][r] *= alpha[r];

        // O += P~ @ Kp_tile
#pragma unroll
        for (int kk = 0; kk < 2; ++kk) {
            bf16x8 a = *(const bf16x8*)&mbs[w * 16 + l16][kk * 32 + quad * 8];
#pragma unroll
            for (int ct = 0; ct < 4; ++ct) {
                bf16x8 bb = *(const bf16x8*)&kts[ct * 16 + l16][kk * 32 + quad * 8];
                oacc[ct] = __builtin_amdgcn_mfma_f32_16x16x32_bf16(a, bb, oacc[ct], 0, 0, 0);
            }
        }
    }

#pragma unroll
    for (int ct = 0; ct < 4; ++ct)
#pragma unroll
        for (int r = 0; r < 4; ++r) {
            int row = q0 + w * 16 + quad * 4 + r;
            int col = ct * 16 + l16;
            float v = oacc[ct][r] / l_run[r];
            om[base + (size_t)row * DM_ + col] = f2bf(v);
        }
}

// ---------------------------------------------------------------------------
extern "C" void kernel_launch(void* const* d_in, const int* in_sizes, int n_in,
                              void* d_out, int out_size, void* d_ws, size_t ws_size,
                              hipStream_t stream)
{
    const void* query = d_in[0];
    const void* key   = d_in[1];
    const void* value = d_in[2];
    const int*  mask  = (const int*)d_in[3];
    const void* Wq  = d_in[4];  const void* bq  = d_in[5];
    const void* Wk  = d_in[6];  const void* bk  = d_in[7];
    const void* Wv  = d_in[8];  const void* bv  = d_in[9];
    const void* Wo  = d_in[10]; const void* bo  = d_in[11];
    const void* Wkl = d_in[12]; const void* bkl = d_in[13];
    const void* Wql = d_in[14]; const void* bql = d_in[15];
    const void* Wq2 = d_in[16]; const void* bq2 = d_in[17];
    const void* Wvl = d_in[18]; const void* bvl = d_in[19];
    const void* Wel = d_in[20]; const void* bel = d_in[21];

    int* flag = (int*)d_ws;
    u16* ws   = (u16*)((char*)d_ws + 16);
    const size_t BUF = (size_t)(B_ * S_) * DM_;   // 4M elements = 8 MB bf16
    u16* Qp  = ws + 0 * BUF;
    u16* Kp  = ws + 1 * BUF;
    u16* Vp  = ws + 2 * BUF;
    u16* krb = ws + 3 * BUF;
    u16* q1a = ws + 4 * BUF;
    u16* q1b = ws + 5 * BUF;
    u16* q2r = ws + 6 * BUF;
    u16* vrb = ws + 7 * BUF;
    u16* Om  = ws + 8 * BUF;
    u16* KpT = Vp;   // alias: Vp's last read is the vrb GEMM, before transpose
    u16* mb  = Kp;   // alias: Kp's last read is the transpose, before maskbias

    const int M = B_ * S_;            // 4096
    dim3 blk(256);
    dim3 gBig(DM_ / 64, M / 128);     // (16, 32) = 512 blocks
    dim3 gSm(1, (M * H_) / 128);      // (1, 512): M=65536, N=K=64

    detect_kernel<<<1, 64, 0, stream>>>((const u16*)query, flag);

    // projections: A and W dtype-dynamic, out bf16 ws
    gemm_bias_kernel<0,1,1,0><<<gBig, blk, 0, stream>>>(query, Wq, bq, Qp, M, DM_, DM_, flag);
    gemm_bias_kernel<0,1,1,0><<<gBig, blk, 0, stream>>>(key,   Wk, bk, Kp, M, DM_, DM_, flag);
    gemm_bias_kernel<0,1,1,0><<<gBig, blk, 0, stream>>>(value, Wv, bv, Vp, M, DM_, DM_, flag);

    // per-head refinements as (65536,64)x(64,64) GEMMs; A is ws bf16, W dynamic
    gemm_bias_kernel<1,0,1,0><<<gSm, blk, 0, stream>>>(Kp,  Wkl, bkl, krb, M * H_, DK_, DK_, flag);
    gemm_bias_kernel<1,0,1,0><<<gSm, blk, 0, stream>>>(Qp,  Wql, bql, q1a, M * H_, DK_, DK_, flag);
    gemm_bias_kernel<1,0,1,0><<<gSm, blk, 0, stream>>>(q1a, Wel, bel, q1b, M * H_, DK_, DK_, flag);
    gemm_bias_kernel<1,0,1,0><<<gSm, blk, 0, stream>>>(Qp,  Wq2, bq2, q2r, M * H_, DK_, DK_, flag);
    gemm_bias_kernel<1,0,1,0><<<gSm, blk, 0, stream>>>(Vp,  Wvl, bvl, vrb, M * H_, DK_, DK_, flag);

    // Kp -> per-head transposed copy (after all reads of Vp slot)
    dim3 gT(S_ / 64, H_, B_);
    transpose_kernel<<<gT, blk, 0, stream>>>(Kp, KpT);

    // mask -> additive bf16 bias (after last read of Kp slot)
    maskbias_kernel<<<dim3((B_ * S_ * S_) / (256 * 8)), blk, 0, stream>>>(mask, mb);

    // fused attention -> merged (B,S,DM) layout
    dim3 gA(S_ / 64, H_, B_);         // (16,16,4)
    attn_kernel<<<gA, blk, 0, stream>>>(q1b, q2r, krb, vrb, KpT, mb, Om);

    // output projection straight into d_out; out dtype runtime-selected
    gemm_bias_kernel<0,0,1,1><<<gBig, blk, 0, stream>>>(Om, Wo, bo, d_out, M, DM_, DM_, flag);
}

// Round 4
// 451.398 us; speedup vs baseline: 1.1423x; 1.1423x over previous
//
#include <hip/hip_runtime.h>
#include <hip/hip_bf16.h>

#define B_  4
#define S_  1024
#define DM_ 1024
#define H_  16
#define DK_ 64

typedef unsigned short u16;
typedef __attribute__((ext_vector_type(8))) short bf16x8;
typedef __attribute__((ext_vector_type(4))) float f32x4;

__device__ __forceinline__ float bf2f(u16 u) {
    union { unsigned int i; float f; } c;
    c.i = ((unsigned int)u) << 16;
    return c.f;
}
__device__ __forceinline__ u16 f2bf(float f) {
    union { float f; unsigned int i; } c;
    c.f = f;
    unsigned int x = c.i;
    unsigned int lsb = (x >> 16) & 1u;
    x += 0x7fffu + lsb;          // round-to-nearest-even
    return (u16)(x >> 16);
}

// ---------------------------------------------------------------------------
// Runtime dtype detection (one wave). fp32 inputs -> even u16s are float low
// halves (mantissa bits, ~16% in exponent range); bf16 -> ~100%. flag=1: fp32.
// ---------------------------------------------------------------------------
__global__ void detect_kernel(const u16* __restrict__ q, int* __restrict__ flag) {
    int lane = threadIdx.x & 63;
    int cnt = 0;
#pragma unroll
    for (int i = 0; i < 4; ++i) {
        u16 u = q[2 * (lane * 4 + i)];
        int e = (u >> 7) & 0xFF;
        cnt += (e >= 100 && e <= 140) ? 1 : 0;
    }
#pragma unroll
    for (int off = 1; off < 64; off <<= 1) cnt += __shfl_xor(cnt, off, 64);
    if (lane == 0) *flag = (cnt < 128) ? 1 : 0;
}

// ---------------------------------------------------------------------------
// Packed multi-tensor dtype normalization: for each segment, dst(bf16) <-
// src (fp32 converted, or bf16 copied, per *flag). One launch for all 12
// tensors; vec = 8 elements (uint4 in bf16).
// ---------------------------------------------------------------------------
#define NSEG 12
struct CvtArgs {
    const void* src[NSEG];
    void*       dst[NSEG];
    unsigned    off[NSEG + 1];   // cumulative vec offsets
};

__global__ __launch_bounds__(256) void convert_kernel(
    CvtArgs a, unsigned total, const int* __restrict__ flag)
{
    unsigned v = blockIdx.x * 256 + threadIdx.x;
    if (v >= total) return;
    int s = 0;
    while (s < NSEG - 1 && v >= a.off[s + 1]) ++s;
    unsigned local = v - a.off[s];
    u16* dp = (u16*)a.dst[s] + (size_t)local * 8;
    if (*flag) {
        const float* sp = (const float*)a.src[s] + (size_t)local * 8;
        float4 x = *(const float4*)sp, y = *(const float4*)(sp + 4);
        u16 t[8] = {f2bf(x.x), f2bf(x.y), f2bf(x.z), f2bf(x.w),
                    f2bf(y.x), f2bf(y.y), f2bf(y.z), f2bf(y.w)};
        *(uint4*)dp = *(uint4*)t;
    } else {
        *(uint4*)dp = *(const uint4*)((const u16*)a.src[s] + (size_t)local * 8);
    }
}

// ---------------------------------------------------------------------------
// mask (int32) -> additive bf16 bias: 0 where mask!=0, -1e9 where mask==0.
// ---------------------------------------------------------------------------
__global__ __launch_bounds__(256) void maskbias_kernel(
    const int* __restrict__ mask, u16* __restrict__ mb)
{
    size_t i = ((size_t)blockIdx.x * 256 + threadIdx.x) * 8;
    int4 m0 = *(const int4*)&mask[i];
    int4 m1 = *(const int4*)&mask[i + 4];
    const u16 NEG = f2bf(-1e9f);
    u16 o[8];
    o[0] = m0.x ? 0 : NEG; o[1] = m0.y ? 0 : NEG;
    o[2] = m0.z ? 0 : NEG; o[3] = m0.w ? 0 : NEG;
    o[4] = m1.x ? 0 : NEG; o[5] = m1.y ? 0 : NEG;
    o[6] = m1.z ? 0 : NEG; o[7] = m1.w ? 0 : NEG;
    *(uint4*)&mb[i] = *(uint4*)o;
}

// ---------------------------------------------------------------------------
// Per-head transpose: Kp (b,s,h,d) -> KpT[((b*H+h)*DK + d)*S + s].
// ---------------------------------------------------------------------------
__global__ __launch_bounds__(256) void transpose_kernel(
    const u16* __restrict__ kp, u16* __restrict__ kpt)
{
    __shared__ u16 T[64][65];
    const int s0 = blockIdx.x * 64, h = blockIdx.y, b = blockIdx.z;
    const int tid = threadIdx.x;
    const size_t base = (size_t)b * S_ * DM_ + (size_t)h * DK_;
    for (int c = tid; c < 512; c += 256) {
        int row = c >> 3, cc = (c & 7) * 8;
        union { uint4 v; u16 u[8]; } x;
        x.v = *(const uint4*)&kp[base + (size_t)(s0 + row) * DM_ + cc];
#pragma unroll
        for (int j = 0; j < 8; ++j) T[row][cc + j] = x.u[j];
    }
    __syncthreads();
    const size_t baseT = (size_t)(b * H_ + h) * DK_ * S_;
    for (int c = tid; c < 512; c += 256) {
        int d = c >> 3, ss = (c & 7) * 8;
        u16 t[8];
#pragma unroll
        for (int j = 0; j < 8; ++j) t[j] = T[ss + j][d];
        *(uint4*)&kpt[baseT + (size_t)d * S_ + s0 + ss] = *(uint4*)t;
    }
}

// ---------------------------------------------------------------------------
// GEMM (all-bf16 operands): C[m,n] = act(sum_k A[m,k]*W[n,k] + bias[n]);
// bf16 MFMA, fp32 accum. 128x64 tile (BK=64), 256 threads; wave w owns rows
// w*32..w*32+31 (2 row-tiles x 4 col-tiles of mfma_f32_16x16x32_bf16).
// BIAS_DYN/OUT_DYN: bias read / C store dtype selected by runtime *flag.
// ---------------------------------------------------------------------------
template<int ACT, int BIAS_DYN, int OUT_DYN>
__global__ __launch_bounds__(256, 2) void gemm_bias_kernel(
    const u16* __restrict__ A, const u16* __restrict__ W,
    const void* __restrict__ biasp, void* __restrict__ Cp,
    int M, int N, int K, const int* __restrict__ flag)
{
    __shared__ __align__(16) u16 As[128][72];
    __shared__ __align__(16) u16 Ws[64][72];

    const int f = (BIAS_DYN || OUT_DYN) ? *flag : 0;

    const int m0   = blockIdx.y * 128;
    const int n0   = blockIdx.x * 64;
    const int tid  = threadIdx.x;
    const int w    = tid >> 6;
    const int lane = tid & 63;
    const int l16  = lane & 15;
    const int quad = lane >> 4;

    f32x4 acc[2][4];
#pragma unroll
    for (int rt = 0; rt < 2; ++rt)
#pragma unroll
        for (int ct = 0; ct < 4; ++ct) acc[rt][ct] = (f32x4){0.f, 0.f, 0.f, 0.f};

    for (int k0 = 0; k0 < K; k0 += 64) {
#pragma unroll
        for (int c = tid; c < 1024; c += 256) {
            int row = c >> 3, cc = (c & 7) * 8;
            *(uint4*)&As[row][cc] = *(const uint4*)&A[(size_t)(m0 + row) * K + k0 + cc];
        }
#pragma unroll
        for (int c = tid; c < 512; c += 256) {
            int row = c >> 3, cc = (c & 7) * 8;
            *(uint4*)&Ws[row][cc] = *(const uint4*)&W[(size_t)(n0 + row) * K + k0 + cc];
        }
        __syncthreads();
#pragma unroll
        for (int kk = 0; kk < 2; ++kk) {
            bf16x8 a[2], b[4];
#pragma unroll
            for (int rt = 0; rt < 2; ++rt)
                a[rt] = *(const bf16x8*)&As[w * 32 + rt * 16 + l16][kk * 32 + quad * 8];
#pragma unroll
            for (int ct = 0; ct < 4; ++ct)
                b[ct] = *(const bf16x8*)&Ws[ct * 16 + l16][kk * 32 + quad * 8];
#pragma unroll
            for (int rt = 0; rt < 2; ++rt)
#pragma unroll
                for (int ct = 0; ct < 4; ++ct)
                    acc[rt][ct] = __builtin_amdgcn_mfma_f32_16x16x32_bf16(
                        a[rt], b[ct], acc[rt][ct], 0, 0, 0);
        }
        __syncthreads();
    }

    // C/D layout: row = quad*4 + r, col = l16 (m89/m91)
#pragma unroll
    for (int ct = 0; ct < 4; ++ct) {
        int col = n0 + ct * 16 + l16;
        float bv = (BIAS_DYN && f) ? ((const float*)biasp)[col]
                                   : bf2f(((const u16*)biasp)[col]);
#pragma unroll
        for (int rt = 0; rt < 2; ++rt)
#pragma unroll
            for (int r = 0; r < 4; ++r) {
                int row = m0 + w * 32 + rt * 16 + quad * 4 + r;
                float v = acc[rt][ct][r] + bv;
                if (ACT) v = v > 0.f ? v : 0.f;
                size_t idx = (size_t)row * N + col;
                if (OUT_DYN && f) ((float*)Cp)[idx] = v;
                else              ((u16*)Cp)[idx]   = f2bf(v);
            }
    }
}

// ---------------------------------------------------------------------------
// Fused attention, flash-style (unchanged from R3). One block = (b,h,q-tile).
// ---------------------------------------------------------------------------
__global__ __launch_bounds__(256, 4) void attn_kernel(
    const u16* __restrict__ q1, const u16* __restrict__ q2,
    const u16* __restrict__ kr, const u16* __restrict__ vr,
    const u16* __restrict__ kpt, const u16* __restrict__ mb,
    u16* __restrict__ om)
{
    __shared__ __align__(16) u16 krs[64][72];
    __shared__ __align__(16) u16 vrs[64][72];
    __shared__ __align__(16) u16 kts[64][72];   // KpT tile: rows d, cols k
    __shared__ __align__(16) u16 mbs[64][72];   // mask bias; pts aliases rows w*16..

    const int qt   = blockIdx.x;
    const int h    = blockIdx.y;
    const int b    = blockIdx.z;
    const int q0   = qt * 64;
    const int tid  = threadIdx.x;
    const int w    = tid >> 6;
    const int lane = tid & 63;
    const int l16  = lane & 15;
    const int quad = lane >> 4;

    const size_t base  = (size_t)b * S_ * DM_ + (size_t)h * DK_;
    const size_t baseT = (size_t)(b * H_ + h) * DK_ * S_;

    const int qrow = q0 + w * 16 + l16;
    bf16x8 a1[2], a2[2];
#pragma unroll
    for (int kk = 0; kk < 2; ++kk) {
        a1[kk] = *(const bf16x8*)&q1[base + (size_t)qrow * DM_ + kk * 32 + quad * 8];
        a2[kk] = *(const bf16x8*)&q2[base + (size_t)qrow * DM_ + kk * 32 + quad * 8];
    }

    float m_run[4], l_run[4];
    f32x4 oacc[4];
#pragma unroll
    for (int r = 0; r < 4; ++r) { m_run[r] = -1e30f; l_run[r] = 0.f; }
#pragma unroll
    for (int ct = 0; ct < 4; ++ct) oacc[ct] = (f32x4){0.f, 0.f, 0.f, 0.f};

    for (int kt = 0; kt < S_ / 64; ++kt) {
        const int k0 = kt * 64;
        __syncthreads();
        for (int c = tid; c < 512; c += 256) {
            int row = c >> 3, cc = (c & 7) * 8;
            *(uint4*)&krs[row][cc] = *(const uint4*)&kr[base + (size_t)(k0 + row) * DM_ + cc];
            *(uint4*)&vrs[row][cc] = *(const uint4*)&vr[base + (size_t)(k0 + row) * DM_ + cc];
            *(uint4*)&kts[row][cc] = *(const uint4*)&kpt[baseT + (size_t)row * S_ + k0 + cc];
            *(uint4*)&mbs[row][cc] = *(const uint4*)&mb[((size_t)b * S_ + q0 + row) * S_ + k0 + cc];
        }
        __syncthreads();

        f32x4 s1[4], s2[4];
#pragma unroll
        for (int ct = 0; ct < 4; ++ct) {
            s1[ct] = (f32x4){0.f, 0.f, 0.f, 0.f};
            s2[ct] = (f32x4){0.f, 0.f, 0.f, 0.f};
        }
#pragma unroll
        for (int kk = 0; kk < 2; ++kk) {
#pragma unroll
            for (int ct = 0; ct < 4; ++ct) {
                bf16x8 b1 = *(const bf16x8*)&krs[ct * 16 + l16][kk * 32 + quad * 8];
                bf16x8 b2 = *(const bf16x8*)&vrs[ct * 16 + l16][kk * 32 + quad * 8];
                s1[ct] = __builtin_amdgcn_mfma_f32_16x16x32_bf16(a1[kk], b1, s1[ct], 0, 0, 0);
                s2[ct] = __builtin_amdgcn_mfma_f32_16x16x32_bf16(a2[kk], b2, s2[ct], 0, 0, 0);
            }
        }

        float tmax[4] = {-1e30f, -1e30f, -1e30f, -1e30f};
#pragma unroll
        for (int ct = 0; ct < 4; ++ct)
#pragma unroll
            for (int r = 0; r < 4; ++r) {
                float v = s1[ct][r] + bf2f(mbs[w * 16 + quad * 4 + r][ct * 16 + l16]);
                s1[ct][r] = v;
                tmax[r] = fmaxf(tmax[r], v);
            }
#pragma unroll
        for (int off = 1; off < 16; off <<= 1)
#pragma unroll
            for (int r = 0; r < 4; ++r)
                tmax[r] = fmaxf(tmax[r], __shfl_xor(tmax[r], off, 64));

        float alpha[4], newm[4];
#pragma unroll
        for (int r = 0; r < 4; ++r) {
            newm[r]  = fmaxf(m_run[r], tmax[r]);
            alpha[r] = __expf(m_run[r] - newm[r]);
            m_run[r] = newm[r];
        }

        float psum[4] = {0.f, 0.f, 0.f, 0.f};
#pragma unroll
        for (int ct = 0; ct < 4; ++ct)
#pragma unroll
            for (int r = 0; r < 4; ++r) {
                float p = __expf(s1[ct][r] - newm[r]);
                psum[r] += p;
                mbs[w * 16 + quad * 4 + r][ct * 16 + l16] = f2bf(p * s2[ct][r]);
            }
#pragma unroll
        for (int off = 1; off < 16; off <<= 1)
#pragma unroll
            for (int r = 0; r < 4; ++r)
                psum[r] += __shfl_xor(psum[r], off, 64);
#pragma unroll
        for (int r = 0; r < 4; ++r) l_run[r] = l_run[r] * alpha[r] + psum[r];
#pragma unroll
        for (int ct = 0; ct < 4; ++ct)
#pragma unroll
            for (int r = 0; r < 4; ++r) oacc[ct][r] *= alpha[r];

#pragma unroll
        for (int kk = 0; kk < 2; ++kk) {
            bf16x8 a = *(const bf16x8*)&mbs[w * 16 + l16][kk * 32 + quad * 8];
#pragma unroll
            for (int ct = 0; ct < 4; ++ct) {
                bf16x8 bb = *(const bf16x8*)&kts[ct * 16 + l16][kk * 32 + quad * 8];
                oacc[ct] = __builtin_amdgcn_mfma_f32_16x16x32_bf16(a, bb, oacc[ct], 0, 0, 0);
            }
        }
    }

#pragma unroll
    for (int ct = 0; ct < 4; ++ct)
#pragma unroll
        for (int r = 0; r < 4; ++r) {
            int row = q0 + w * 16 + quad * 4 + r;
            int col = ct * 16 + l16;
            float v = oacc[ct][r] / l_run[r];
            om[base + (size_t)row * DM_ + col] = f2bf(v);
        }
}

// ---------------------------------------------------------------------------
extern "C" void kernel_launch(void* const* d_in, const int* in_sizes, int n_in,
                              void* d_out, int out_size, void* d_ws, size_t ws_size,
                              hipStream_t stream)
{
    const void* query = d_in[0];
    const void* key   = d_in[1];
    const void* value = d_in[2];
    const int*  mask  = (const int*)d_in[3];
    const void* Wq  = d_in[4];  const void* bq  = d_in[5];
    const void* Wk  = d_in[6];  const void* bk  = d_in[7];
    const void* Wv  = d_in[8];  const void* bv  = d_in[9];
    const void* Wo  = d_in[10]; const void* bo  = d_in[11];
    const void* Wkl = d_in[12]; const void* bkl = d_in[13];
    const void* Wql = d_in[14]; const void* bql = d_in[15];
    const void* Wq2 = d_in[16]; const void* bq2 = d_in[17];
    const void* Wvl = d_in[18]; const void* bvl = d_in[19];
    const void* Wel = d_in[20]; const void* bel = d_in[21];

    int* flag = (int*)d_ws;
    u16* ws   = (u16*)((char*)d_ws + 16);
    const size_t BUF = (size_t)(B_ * S_) * DM_;   // 4M elems = 8 MB bf16
    u16* Qp  = ws + 0 * BUF;
    u16* Kp  = ws + 1 * BUF;
    u16* Vp  = ws + 2 * BUF;
    u16* krb = ws + 3 * BUF;
    u16* q1a = ws + 4 * BUF;
    u16* q1b = ws + 5 * BUF;
    u16* q2r = ws + 6 * BUF;
    u16* vrb = ws + 7 * BUF;
    u16* Om  = ws + 8 * BUF;
    u16* Qc  = ws + 9 * BUF;    // bf16-normalized inputs
    u16* Kc  = ws + 10 * BUF;
    u16* Vc  = ws + 11 * BUF;
    u16* Wbig = ws + 12 * BUF;  // 4 x 1M-elem big weights
    u16* Wqc = Wbig + 0 * (size_t)(DM_ * DM_);
    u16* Wkc = Wbig + 1 * (size_t)(DM_ * DM_);
    u16* Wvc = Wbig + 2 * (size_t)(DM_ * DM_);
    u16* Woc = Wbig + 3 * (size_t)(DM_ * DM_);
    u16* Wsm = Wbig + 4 * (size_t)(DM_ * DM_);  // 5 x 4096-elem small weights
    u16* Wklc = Wsm + 0 * (DK_ * DK_);
    u16* Wqlc = Wsm + 1 * (DK_ * DK_);
    u16* Welc = Wsm + 2 * (DK_ * DK_);
    u16* Wq2c = Wsm + 3 * (DK_ * DK_);
    u16* Wvlc = Wsm + 4 * (DK_ * DK_);
    u16* KpT = Vp;   // alias: Vp's last read is the vrb GEMM, before transpose
    u16* mb  = Kp;   // alias: Kp's last read is the transpose, before maskbias

    const int M = B_ * S_;            // 4096
    dim3 blk(256);
    dim3 gBig(DM_ / 64, M / 128);     // (16, 32) = 512 blocks
    dim3 gSm(1, (M * H_) / 128);      // (1, 512): M=65536, N=K=64

    detect_kernel<<<1, 64, 0, stream>>>((const u16*)query, flag);

    // normalize all fp-dtype tensors to bf16 in one launch
    CvtArgs ca;
    const unsigned VIN = (unsigned)(BUF / 8);            // 524288
    const unsigned VWB = (unsigned)(DM_ * DM_ / 8);      // 131072
    const unsigned VWS = (unsigned)(DK_ * DK_ / 8);      // 512
    const void* srcs[NSEG] = {query, key, value, Wq, Wk, Wv, Wo, Wkl, Wql, Wel, Wq2, Wvl};
    void* dsts[NSEG] = {Qc, Kc, Vc, Wqc, Wkc, Wvc, Woc, Wklc, Wqlc, Welc, Wq2c, Wvlc};
    unsigned vc[NSEG] = {VIN, VIN, VIN, VWB, VWB, VWB, VWB, VWS, VWS, VWS, VWS, VWS};
    unsigned off = 0;
    for (int i = 0; i < NSEG; ++i) { ca.src[i] = srcs[i]; ca.dst[i] = dsts[i]; ca.off[i] = off; off += vc[i]; }
    ca.off[NSEG] = off;
    convert_kernel<<<dim3((off + 255) / 256), blk, 0, stream>>>(ca, off, flag);

    // projections (all-bf16; bias dtype-dynamic)
    gemm_bias_kernel<0,1,0><<<gBig, blk, 0, stream>>>(Qc, Wqc, bq, Qp, M, DM_, DM_, flag);
    gemm_bias_kernel<0,1,0><<<gBig, blk, 0, stream>>>(Kc, Wkc, bk, Kp, M, DM_, DM_, flag);
    gemm_bias_kernel<0,1,0><<<gBig, blk, 0, stream>>>(Vc, Wvc, bv, Vp, M, DM_, DM_, flag);

    // per-head refinements as (65536,64)x(64,64) GEMMs
    gemm_bias_kernel<1,1,0><<<gSm, blk, 0, stream>>>(Kp,  Wklc, bkl, krb, M * H_, DK_, DK_, flag);
    gemm_bias_kernel<1,1,0><<<gSm, blk, 0, stream>>>(Qp,  Wqlc, bql, q1a, M * H_, DK_, DK_, flag);
    gemm_bias_kernel<1,1,0><<<gSm, blk, 0, stream>>>(q1a, Welc, bel, q1b, M * H_, DK_, DK_, flag);
    gemm_bias_kernel<1,1,0><<<gSm, blk, 0, stream>>>(Qp,  Wq2c, bq2, q2r, M * H_, DK_, DK_, flag);
    gemm_bias_kernel<1,1,0><<<gSm, blk, 0, stream>>>(Vp,  Wvlc, bvl, vrb, M * H_, DK_, DK_, flag);

    // Kp -> per-head transposed copy (after all reads of Vp slot)
    dim3 gT(S_ / 64, H_, B_);
    transpose_kernel<<<gT, blk, 0, stream>>>(Kp, KpT);

    // mask -> additive bf16 bias (after last read of Kp slot)
    maskbias_kernel<<<dim3((B_ * S_ * S_) / (256 * 8)), blk, 0, stream>>>(mask, mb);

    // fused attention -> merged (B,S,DM) layout
    dim3 gA(S_ / 64, H_, B_);         // (16,16,4)
    attn_kernel<<<gA, blk, 0, stream>>>(q1b, q2r, krb, vrb, KpT, mb, Om);

    // output projection straight into d_out; out dtype runtime-selected
    gemm_bias_kernel<0,1,1><<<gBig, blk, 0, stream>>>(Om, Woc, bo, d_out, M, DM_, DM_, flag);
}

// Round 5
// 360.571 us; speedup vs baseline: 1.4301x; 1.2519x over previous
//
#include <hip/hip_runtime.h>
#include <hip/hip_bf16.h>

#define B_  4
#define S_  1024
#define DM_ 1024
#define H_  16
#define DK_ 64

typedef unsigned short u16;
typedef __attribute__((ext_vector_type(8))) short bf16x8;
typedef __attribute__((ext_vector_type(4))) float f32x4;

__device__ __forceinline__ float bf2f(u16 u) {
    union { unsigned int i; float f; } c;
    c.i = ((unsigned int)u) << 16;
    return c.f;
}
__device__ __forceinline__ u16 f2bf(float f) {
    union { float f; unsigned int i; } c;
    c.f = f;
    unsigned int x = c.i;
    unsigned int lsb = (x >> 16) & 1u;
    x += 0x7fffu + lsb;          // round-to-nearest-even
    return (u16)(x >> 16);
}

// async global->LDS, 16B per lane; LDS dest = wave-uniform base + lane*16
__device__ __forceinline__ void async_ld16(const u16* g, u16* l) {
    __builtin_amdgcn_global_load_lds(
        (const __attribute__((address_space(1))) unsigned int*)(const void*)g,
        (__attribute__((address_space(3))) unsigned int*)(void*)l, 16, 0, 0);
}

// ---------------------------------------------------------------------------
// Runtime dtype detection (one wave). flag=1: inputs are fp32.
// ---------------------------------------------------------------------------
__global__ void detect_kernel(const u16* __restrict__ q, int* __restrict__ flag) {
    int lane = threadIdx.x & 63;
    int cnt = 0;
#pragma unroll
    for (int i = 0; i < 4; ++i) {
        u16 u = q[2 * (lane * 4 + i)];
        int e = (u >> 7) & 0xFF;
        cnt += (e >= 100 && e <= 140) ? 1 : 0;
    }
#pragma unroll
    for (int off = 1; off < 64; off <<= 1) cnt += __shfl_xor(cnt, off, 64);
    if (lane == 0) *flag = (cnt < 128) ? 1 : 0;
}

// ---------------------------------------------------------------------------
// Packed multi-tensor dtype normalization to bf16 (fp32-convert or copy).
// ---------------------------------------------------------------------------
#define NSEG 12
struct CvtArgs {
    const void* src[NSEG];
    void*       dst[NSEG];
    unsigned    off[NSEG + 1];
};

__global__ __launch_bounds__(256) void convert_kernel(
    CvtArgs a, unsigned total, const int* __restrict__ flag)
{
    unsigned v = blockIdx.x * 256 + threadIdx.x;
    if (v >= total) return;
    int s = 0;
    while (s < NSEG - 1 && v >= a.off[s + 1]) ++s;
    unsigned local = v - a.off[s];
    u16* dp = (u16*)a.dst[s] + (size_t)local * 8;
    if (*flag) {
        const float* sp = (const float*)a.src[s] + (size_t)local * 8;
        float4 x = *(const float4*)sp, y = *(const float4*)(sp + 4);
        u16 t[8] = {f2bf(x.x), f2bf(x.y), f2bf(x.z), f2bf(x.w),
                    f2bf(y.x), f2bf(y.y), f2bf(y.z), f2bf(y.w)};
        *(uint4*)dp = *(uint4*)t;
    } else {
        *(uint4*)dp = *(const uint4*)((const u16*)a.src[s] + (size_t)local * 8);
    }
}

// ---------------------------------------------------------------------------
// mask (int32) -> additive bf16 bias: 0 where mask!=0, -1e9 where mask==0.
// ---------------------------------------------------------------------------
__global__ __launch_bounds__(256) void maskbias_kernel(
    const int* __restrict__ mask, u16* __restrict__ mb)
{
    size_t i = ((size_t)blockIdx.x * 256 + threadIdx.x) * 8;
    int4 m0 = *(const int4*)&mask[i];
    int4 m1 = *(const int4*)&mask[i + 4];
    const u16 NEG = f2bf(-1e9f);
    u16 o[8];
    o[0] = m0.x ? 0 : NEG; o[1] = m0.y ? 0 : NEG;
    o[2] = m0.z ? 0 : NEG; o[3] = m0.w ? 0 : NEG;
    o[4] = m1.x ? 0 : NEG; o[5] = m1.y ? 0 : NEG;
    o[6] = m1.z ? 0 : NEG; o[7] = m1.w ? 0 : NEG;
    *(uint4*)&mb[i] = *(uint4*)o;
}

// ---------------------------------------------------------------------------
// Per-head transpose: Kp (b,s,h,d) -> KpT[((b*H+h)*DK + d)*S + s].
// ---------------------------------------------------------------------------
__global__ __launch_bounds__(256) void transpose_kernel(
    const u16* __restrict__ kp, u16* __restrict__ kpt)
{
    __shared__ u16 T[64][65];
    const int s0 = blockIdx.x * 64, h = blockIdx.y, b = blockIdx.z;
    const int tid = threadIdx.x;
    const size_t base = (size_t)b * S_ * DM_ + (size_t)h * DK_;
    for (int c = tid; c < 512; c += 256) {
        int row = c >> 3, cc = (c & 7) * 8;
        union { uint4 v; u16 u[8]; } x;
        x.v = *(const uint4*)&kp[base + (size_t)(s0 + row) * DM_ + cc];
#pragma unroll
        for (int j = 0; j < 8; ++j) T[row][cc + j] = x.u[j];
    }
    __syncthreads();
    const size_t baseT = (size_t)(b * H_ + h) * DK_ * S_;
    for (int c = tid; c < 512; c += 256) {
        int d = c >> 3, ss = (c & 7) * 8;
        u16 t[8];
#pragma unroll
        for (int j = 0; j < 8; ++j) t[j] = T[ss + j][d];
        *(uint4*)&kpt[baseT + (size_t)d * S_ + s0 + ss] = *(uint4*)t;
    }
}

// ---------------------------------------------------------------------------
// Batched descriptor: up to 4 (A, W, bias, C) GEMMs of identical M,N,K,
// selected by blockIdx.z.
// ---------------------------------------------------------------------------
struct GemmBatch {
    const u16* A[4];
    const u16* W[4];
    const void* bias[4];
    void* C[4];
};

// ---------------------------------------------------------------------------
// Big GEMM, m97 structure: 128x128 tile, BK=64, async global->LDS staging
// (global_load_lds dwordx4), unpadded LDS with XOR column-group swizzle
// p = g ^ (row&7) -> frag ds_read_b128 hits each bank pair-wise (free).
// 4 waves in 2x2; each wave owns a 64x64 quadrant (4x4 16x16x32 MFMAs).
// ---------------------------------------------------------------------------
template<int ACT, int BIAS_DYN, int OUT_DYN>
__global__ __launch_bounds__(256, 3) void gemm_async_kernel(
    GemmBatch gb, int M, int N, int K, const int* __restrict__ flag)
{
    __shared__ __align__(16) u16 As[128][64];
    __shared__ __align__(16) u16 Ws[128][64];

    const int g = blockIdx.z;
    const u16* __restrict__ A = gb.A[g];
    const u16* __restrict__ W = gb.W[g];
    const void* biasp = gb.bias[g];
    void* Cp = gb.C[g];
    const int f = (BIAS_DYN || OUT_DYN) ? *flag : 0;

    const int m0   = blockIdx.y * 128;
    const int n0   = blockIdx.x * 128;
    const int tid  = threadIdx.x;
    const int w    = tid >> 6;
    const int lane = tid & 63;
    const int l16  = lane & 15;
    const int quad = lane >> 4;
    const int wr   = (w >> 1) * 64;   // wave quadrant row
    const int wc   = (w & 1) * 64;    // wave quadrant col

    // staging: lane covers row (lane>>3) of its 8-row segment, swizzled group
    const int srow = lane >> 3;
    const int sgrp = (lane & 7) ^ srow;

    f32x4 acc[4][4];
#pragma unroll
    for (int rt = 0; rt < 4; ++rt)
#pragma unroll
        for (int ct = 0; ct < 4; ++ct) acc[rt][ct] = (f32x4){0.f, 0.f, 0.f, 0.f};

    for (int k0 = 0; k0 < K; k0 += 64) {
#pragma unroll
        for (int s = 0; s < 4; ++s) {
            int seg = w * 4 + s;                 // wave-uniform
            async_ld16(&A[(size_t)(m0 + seg * 8 + srow) * K + k0 + sgrp * 8],
                       &As[seg * 8][0]);
            async_ld16(&W[(size_t)(n0 + seg * 8 + srow) * K + k0 + sgrp * 8],
                       &Ws[seg * 8][0]);
        }
        __syncthreads();
#pragma unroll
        for (int kk = 0; kk < 2; ++kk) {
            const int p = (kk * 4 + quad) ^ (l16 & 7);   // swizzled group
            bf16x8 av[4], bv[4];
#pragma unroll
            for (int rt = 0; rt < 4; ++rt)
                av[rt] = *(const bf16x8*)&As[wr + rt * 16 + l16][p * 8];
#pragma unroll
            for (int ct = 0; ct < 4; ++ct)
                bv[ct] = *(const bf16x8*)&Ws[wc + ct * 16 + l16][p * 8];
#pragma unroll
            for (int rt = 0; rt < 4; ++rt)
#pragma unroll
                for (int ct = 0; ct < 4; ++ct)
                    acc[rt][ct] = __builtin_amdgcn_mfma_f32_16x16x32_bf16(
                        av[rt], bv[ct], acc[rt][ct], 0, 0, 0);
        }
        __syncthreads();
    }

    // C/D layout: row = quad*4 + r, col = l16 (m89/m91)
#pragma unroll
    for (int ct = 0; ct < 4; ++ct) {
        int col = n0 + wc + ct * 16 + l16;
        float bv = (BIAS_DYN && f) ? ((const float*)biasp)[col]
                                   : bf2f(((const u16*)biasp)[col]);
#pragma unroll
        for (int rt = 0; rt < 4; ++rt)
#pragma unroll
            for (int r = 0; r < 4; ++r) {
                int row = m0 + wr + rt * 16 + quad * 4 + r;
                float v = acc[rt][ct][r] + bv;
                if (ACT) v = v > 0.f ? v : 0.f;
                size_t idx = (size_t)row * N + col;
                if (OUT_DYN && f) ((float*)Cp)[idx] = v;
                else              ((u16*)Cp)[idx]   = f2bf(v);
            }
    }
}

// ---------------------------------------------------------------------------
// Small GEMM (N=K=64, memory-bound): 128x64 tile, single K-iter, batched.
// ---------------------------------------------------------------------------
template<int ACT, int BIAS_DYN, int OUT_DYN>
__global__ __launch_bounds__(256, 2) void gemm_small_kernel(
    GemmBatch gb, int M, int N, int K, const int* __restrict__ flag)
{
    __shared__ __align__(16) u16 As[128][72];
    __shared__ __align__(16) u16 Ws[64][72];

    const int g = blockIdx.z;
    const u16* __restrict__ A = gb.A[g];
    const u16* __restrict__ W = gb.W[g];
    const void* biasp = gb.bias[g];
    void* Cp = gb.C[g];
    const int f = (BIAS_DYN || OUT_DYN) ? *flag : 0;

    const int m0   = blockIdx.y * 128;
    const int n0   = blockIdx.x * 64;
    const int tid  = threadIdx.x;
    const int w    = tid >> 6;
    const int lane = tid & 63;
    const int l16  = lane & 15;
    const int quad = lane >> 4;

    f32x4 acc[2][4];
#pragma unroll
    for (int rt = 0; rt < 2; ++rt)
#pragma unroll
        for (int ct = 0; ct < 4; ++ct) acc[rt][ct] = (f32x4){0.f, 0.f, 0.f, 0.f};

    for (int k0 = 0; k0 < K; k0 += 64) {
#pragma unroll
        for (int c = tid; c < 1024; c += 256) {
            int row = c >> 3, cc = (c & 7) * 8;
            *(uint4*)&As[row][cc] = *(const uint4*)&A[(size_t)(m0 + row) * K + k0 + cc];
        }
#pragma unroll
        for (int c = tid; c < 512; c += 256) {
            int row = c >> 3, cc = (c & 7) * 8;
            *(uint4*)&Ws[row][cc] = *(const uint4*)&W[(size_t)(n0 + row) * K + k0 + cc];
        }
        __syncthreads();
#pragma unroll
        for (int kk = 0; kk < 2; ++kk) {
            bf16x8 a[2], b[4];
#pragma unroll
            for (int rt = 0; rt < 2; ++rt)
                a[rt] = *(const bf16x8*)&As[w * 32 + rt * 16 + l16][kk * 32 + quad * 8];
#pragma unroll
            for (int ct = 0; ct < 4; ++ct)
                b[ct] = *(const bf16x8*)&Ws[ct * 16 + l16][kk * 32 + quad * 8];
#pragma unroll
            for (int rt = 0; rt < 2; ++rt)
#pragma unroll
                for (int ct = 0; ct < 4; ++ct)
                    acc[rt][ct] = __builtin_amdgcn_mfma_f32_16x16x32_bf16(
                        a[rt], b[ct], acc[rt][ct], 0, 0, 0);
        }
        __syncthreads();
    }

#pragma unroll
    for (int ct = 0; ct < 4; ++ct) {
        int col = n0 + ct * 16 + l16;
        float bv = (BIAS_DYN && f) ? ((const float*)biasp)[col]
                                   : bf2f(((const u16*)biasp)[col]);
#pragma unroll
        for (int rt = 0; rt < 2; ++rt)
#pragma unroll
            for (int r = 0; r < 4; ++r) {
                int row = m0 + w * 32 + rt * 16 + quad * 4 + r;
                float v = acc[rt][ct][r] + bv;
                if (ACT) v = v > 0.f ? v : 0.f;
                size_t idx = (size_t)row * N + col;
                if (OUT_DYN && f) ((float*)Cp)[idx] = v;
                else              ((u16*)Cp)[idx]   = f2bf(v);
            }
    }
}

// ---------------------------------------------------------------------------
// Fused attention, flash-style. vs R4: kts LDS array removed — oacc B-frags
// load 16B/lane contiguous from KpT global, issued right after staging to
// overlap the QK/softmax phase. LDS 27.6 KB -> up to 5 blocks/CU.
// ---------------------------------------------------------------------------
__global__ __launch_bounds__(256, 4) void attn_kernel(
    const u16* __restrict__ q1, const u16* __restrict__ q2,
    const u16* __restrict__ kr, const u16* __restrict__ vr,
    const u16* __restrict__ kpt, const u16* __restrict__ mb,
    u16* __restrict__ om)
{
    __shared__ __align__(16) u16 krs[64][72];
    __shared__ __align__(16) u16 vrs[64][72];
    __shared__ __align__(16) u16 mbs[64][72];   // mask bias; pts aliases rows w*16..

    const int qt   = blockIdx.x;
    const int h    = blockIdx.y;
    const int b    = blockIdx.z;
    const int q0   = qt * 64;
    const int tid  = threadIdx.x;
    const int w    = tid >> 6;
    const int lane = tid & 63;
    const int l16  = lane & 15;
    const int quad = lane >> 4;

    const size_t base  = (size_t)b * S_ * DM_ + (size_t)h * DK_;
    const size_t baseT = (size_t)(b * H_ + h) * DK_ * S_;

    const int qrow = q0 + w * 16 + l16;
    bf16x8 a1[2], a2[2];
#pragma unroll
    for (int kk = 0; kk < 2; ++kk) {
        a1[kk] = *(const bf16x8*)&q1[base + (size_t)qrow * DM_ + kk * 32 + quad * 8];
        a2[kk] = *(const bf16x8*)&q2[base + (size_t)qrow * DM_ + kk * 32 + quad * 8];
    }

    float m_run[4], l_run[4];
    f32x4 oacc[4];
#pragma unroll
    for (int r = 0; r < 4; ++r) { m_run[r] = -1e30f; l_run[r] = 0.f; }
#pragma unroll
    for (int ct = 0; ct < 4; ++ct) oacc[ct] = (f32x4){0.f, 0.f, 0.f, 0.f};

    for (int kt = 0; kt < S_ / 64; ++kt) {
        const int k0 = kt * 64;
        __syncthreads();
        for (int c = tid; c < 512; c += 256) {
            int row = c >> 3, cc = (c & 7) * 8;
            *(uint4*)&krs[row][cc] = *(const uint4*)&kr[base + (size_t)(k0 + row) * DM_ + cc];
            *(uint4*)&vrs[row][cc] = *(const uint4*)&vr[base + (size_t)(k0 + row) * DM_ + cc];
            *(uint4*)&mbs[row][cc] = *(const uint4*)&mb[((size_t)b * S_ + q0 + row) * S_ + k0 + cc];
        }
        __syncthreads();

        // KpT B-frags straight from global (16B/lane contiguous); issued early
        // so they are in flight during QK MFMA + softmax VALU.
        bf16x8 bkp[2][4];
#pragma unroll
        for (int kk = 0; kk < 2; ++kk)
#pragma unroll
            for (int ct = 0; ct < 4; ++ct)
                bkp[kk][ct] = *(const bf16x8*)
                    &kpt[baseT + (size_t)(ct * 16 + l16) * S_ + k0 + kk * 32 + quad * 8];

        f32x4 s1[4], s2[4];
#pragma unroll
        for (int ct = 0; ct < 4; ++ct) {
            s1[ct] = (f32x4){0.f, 0.f, 0.f, 0.f};
            s2[ct] = (f32x4){0.f, 0.f, 0.f, 0.f};
        }
#pragma unroll
        for (int kk = 0; kk < 2; ++kk) {
#pragma unroll
            for (int ct = 0; ct < 4; ++ct) {
                bf16x8 b1 = *(const bf16x8*)&krs[ct * 16 + l16][kk * 32 + quad * 8];
                bf16x8 b2 = *(const bf16x8*)&vrs[ct * 16 + l16][kk * 32 + quad * 8];
                s1[ct] = __builtin_amdgcn_mfma_f32_16x16x32_bf16(a1[kk], b1, s1[ct], 0, 0, 0);
                s2[ct] = __builtin_amdgcn_mfma_f32_16x16x32_bf16(a2[kk], b2, s2[ct], 0, 0, 0);
            }
        }

        float tmax[4] = {-1e30f, -1e30f, -1e30f, -1e30f};
#pragma unroll
        for (int ct = 0; ct < 4; ++ct)
#pragma unroll
            for (int r = 0; r < 4; ++r) {
                float v = s1[ct][r] + bf2f(mbs[w * 16 + quad * 4 + r][ct * 16 + l16]);
                s1[ct][r] = v;
                tmax[r] = fmaxf(tmax[r], v);
            }
#pragma unroll
        for (int off = 1; off < 16; off <<= 1)
#pragma unroll
            for (int r = 0; r < 4; ++r)
                tmax[r] = fmaxf(tmax[r], __shfl_xor(tmax[r], off, 64));

        float alpha[4], newm[4];
#pragma unroll
        for (int r = 0; r < 4; ++r) {
            newm[r]  = fmaxf(m_run[r], tmax[r]);
            alpha[r] = __expf(m_run[r] - newm[r]);
            m_run[r] = newm[r];
        }

        float psum[4] = {0.f, 0.f, 0.f, 0.f};
#pragma unroll
        for (int ct = 0; ct < 4; ++ct)
#pragma unroll
            for (int r = 0; r < 4; ++r) {
                float p = __expf(s1[ct][r] - newm[r]);
                psum[r] += p;
                mbs[w * 16 + quad * 4 + r][ct * 16 + l16] = f2bf(p * s2[ct][r]);
            }
#pragma unroll
        for (int off = 1; off < 16; off <<= 1)
#pragma unroll
            for (int r = 0; r < 4; ++r)
                psum[r] += __shfl_xor(psum[r], off, 64);
#pragma unroll
        for (int r = 0; r < 4; ++r) l_run[r] = l_run[r] * alpha[r] + psum[r];
#pragma unroll
        for (int ct = 0; ct < 4; ++ct)
#pragma unroll
            for (int r = 0; r < 4; ++r) oacc[ct][r] *= alpha[r];

        // O += P~ @ Kp_tile (A from own wave's mbs rows; same-wave DS in-order)
#pragma unroll
        for (int kk = 0; kk < 2; ++kk) {
            bf16x8 a = *(const bf16x8*)&mbs[w * 16 + l16][kk * 32 + quad * 8];
#pragma unroll
            for (int ct = 0; ct < 4; ++ct)
                oacc[ct] = __builtin_amdgcn_mfma_f32_16x16x32_bf16(
                    a, bkp[kk][ct], oacc[ct], 0, 0, 0);
        }
    }

#pragma unroll
    for (int ct = 0; ct < 4; ++ct)
#pragma unroll
        for (int r = 0; r < 4; ++r) {
            int row = q0 + w * 16 + quad * 4 + r;
            int col = ct * 16 + l16;
            float v = oacc[ct][r] / l_run[r];
            om[base + (size_t)row * DM_ + col] = f2bf(v);
        }
}

// ---------------------------------------------------------------------------
extern "C" void kernel_launch(void* const* d_in, const int* in_sizes, int n_in,
                              void* d_out, int out_size, void* d_ws, size_t ws_size,
                              hipStream_t stream)
{
    const void* query = d_in[0];
    const void* key   = d_in[1];
    const void* value = d_in[2];
    const int*  mask  = (const int*)d_in[3];
    const void* Wq  = d_in[4];  const void* bq  = d_in[5];
    const void* Wk  = d_in[6];  const void* bk  = d_in[7];
    const void* Wv  = d_in[8];  const void* bv  = d_in[9];
    const void* Wo  = d_in[10]; const void* bo  = d_in[11];
    const void* Wkl = d_in[12]; const void* bkl = d_in[13];
    const void* Wql = d_in[14]; const void* bql = d_in[15];
    const void* Wq2 = d_in[16]; const void* bq2 = d_in[17];
    const void* Wvl = d_in[18]; const void* bvl = d_in[19];
    const void* Wel = d_in[20]; const void* bel = d_in[21];

    int* flag = (int*)d_ws;
    u16* ws   = (u16*)((char*)d_ws + 16);
    const size_t BUF = (size_t)(B_ * S_) * DM_;   // 4M elems = 8 MB bf16
    u16* Qp  = ws + 0 * BUF;
    u16* Kp  = ws + 1 * BUF;
    u16* Vp  = ws + 2 * BUF;
    u16* krb = ws + 3 * BUF;
    u16* q1a = ws + 4 * BUF;
    u16* q1b = ws + 5 * BUF;
    u16* q2r = ws + 6 * BUF;
    u16* vrb = ws + 7 * BUF;
    u16* Om  = ws + 8 * BUF;
    u16* Qc  = ws + 9 * BUF;    // bf16-normalized inputs
    u16* Kc  = ws + 10 * BUF;
    u16* Vc  = ws + 11 * BUF;
    u16* Wbig = ws + 12 * BUF;
    u16* Wqc = Wbig + 0 * (size_t)(DM_ * DM_);
    u16* Wkc = Wbig + 1 * (size_t)(DM_ * DM_);
    u16* Wvc = Wbig + 2 * (size_t)(DM_ * DM_);
    u16* Woc = Wbig + 3 * (size_t)(DM_ * DM_);
    u16* Wsm = Wbig + 4 * (size_t)(DM_ * DM_);
    u16* Wklc = Wsm + 0 * (DK_ * DK_);
    u16* Wqlc = Wsm + 1 * (DK_ * DK_);
    u16* Welc = Wsm + 2 * (DK_ * DK_);
    u16* Wq2c = Wsm + 3 * (DK_ * DK_);
    u16* Wvlc = Wsm + 4 * (DK_ * DK_);
    u16* KpT = Vp;   // alias: Vp's last read is the vrb GEMM (small batch)
    u16* mb  = Kp;   // alias: Kp's last read is the transpose

    const int M = B_ * S_;            // 4096
    dim3 blk(256);

    detect_kernel<<<1, 64, 0, stream>>>((const u16*)query, flag);

    // normalize all fp tensors to bf16 in one launch
    CvtArgs ca;
    const unsigned VIN = (unsigned)(BUF / 8);
    const unsigned VWB = (unsigned)(DM_ * DM_ / 8);
    const unsigned VWS = (unsigned)(DK_ * DK_ / 8);
    const void* srcs[NSEG] = {query, key, value, Wq, Wk, Wv, Wo, Wkl, Wql, Wel, Wq2, Wvl};
    void* dsts[NSEG] = {Qc, Kc, Vc, Wqc, Wkc, Wvc, Woc, Wklc, Wqlc, Welc, Wq2c, Wvlc};
    unsigned vcn[NSEG] = {VIN, VIN, VIN, VWB, VWB, VWB, VWB, VWS, VWS, VWS, VWS, VWS};
    unsigned off = 0;
    for (int i = 0; i < NSEG; ++i) { ca.src[i] = srcs[i]; ca.dst[i] = dsts[i]; ca.off[i] = off; off += vcn[i]; }
    ca.off[NSEG] = off;
    convert_kernel<<<dim3((off + 255) / 256), blk, 0, stream>>>(ca, off, flag);

    // Q/K/V projections batched in one launch (768 blocks -> 3 blocks/CU)
    GemmBatch gqkv = {};
    gqkv.A[0] = Qc;  gqkv.W[0] = Wqc; gqkv.bias[0] = bq; gqkv.C[0] = Qp;
    gqkv.A[1] = Kc;  gqkv.W[1] = Wkc; gqkv.bias[1] = bk; gqkv.C[1] = Kp;
    gqkv.A[2] = Vc;  gqkv.W[2] = Wvc; gqkv.bias[2] = bv; gqkv.C[2] = Vp;
    dim3 gBig(DM_ / 128, M / 128, 3);
    gemm_async_kernel<0,1,0><<<gBig, blk, 0, stream>>>(gqkv, M, DM_, DM_, flag);

    // 4 independent per-head refinements batched (M=65536, N=K=64)
    GemmBatch gref = {};
    gref.A[0] = Kp; gref.W[0] = Wklc; gref.bias[0] = bkl; gref.C[0] = krb;
    gref.A[1] = Qp; gref.W[1] = Wqlc; gref.bias[1] = bql; gref.C[1] = q1a;
    gref.A[2] = Qp; gref.W[2] = Wq2c; gref.bias[2] = bq2; gref.C[2] = q2r;
    gref.A[3] = Vp; gref.W[3] = Wvlc; gref.bias[3] = bvl; gref.C[3] = vrb;
    dim3 gSm(1, (M * H_) / 128, 4);
    gemm_small_kernel<1,1,0><<<gSm, blk, 0, stream>>>(gref, M * H_, DK_, DK_, flag);

    // dependent refinement: q1b = relu(q1a @ Wel^T + bel)
    GemmBatch gel = {};
    gel.A[0] = q1a; gel.W[0] = Welc; gel.bias[0] = bel; gel.C[0] = q1b;
    dim3 gS1(1, (M * H_) / 128, 1);
    gemm_small_kernel<1,1,0><<<gS1, blk, 0, stream>>>(gel, M * H_, DK_, DK_, flag);

    // Kp -> per-head transposed copy (Vp slot free after small batch)
    dim3 gT(S_ / 64, H_, B_);
    transpose_kernel<<<gT, blk, 0, stream>>>(Kp, KpT);

    // mask -> additive bf16 bias (Kp slot free after transpose)
    maskbias_kernel<<<dim3((B_ * S_ * S_) / (256 * 8)), blk, 0, stream>>>(mask, mb);

    // fused attention -> merged (B,S,DM) layout
    dim3 gA(S_ / 64, H_, B_);
    attn_kernel<<<gA, blk, 0, stream>>>(q1b, q2r, krb, vrb, KpT, mb, Om);

    // output projection straight into d_out; out dtype runtime-selected
    GemmBatch go = {};
    go.A[0] = Om; go.W[0] = Woc; go.bias[0] = bo; go.C[0] = (u16*)d_out;
    dim3 gO(DM_ / 128, M / 128, 1);
    gemm_async_kernel<0,1,1><<<gO, blk, 0, stream>>>(go, M, DM_, DM_, flag);
}